// Round 7
// baseline (333.605 us; speedup 1.0000x reference)
//
#include <hip/hip_runtime.h>

#define EPS 1e-6f

// Sizes (fixed): B=4, N=1024, DIM=384, H=12, d=32, BH=48
// ws layout (floats): q[48*1024*32] | k[...] | v[...] | out_pre[4096*384]

// ---------------- Kernel 1: qkv = x @ w_qkv, relu+eps on q,k, scatter to [BH][N][32] ----------------
__global__ __launch_bounds__(256) void qkv_gemm(const float* __restrict__ x,
                                                const float* __restrict__ w,
                                                float* __restrict__ qw,
                                                float* __restrict__ kw,
                                                float* __restrict__ vw) {
    __shared__ float As[32][68];   // transposed A tile: As[k][row]
    __shared__ float Bs[32][68];   // natural B tile:    Bs[k][col]
    const int t = threadIdx.x;
    const int m0 = blockIdx.y * 64;
    const int c0 = blockIdx.x * 64;
    const int tx = t & 15, ty = t >> 4;

    float acc[4][4];
#pragma unroll
    for (int i = 0; i < 4; i++)
#pragma unroll
        for (int j = 0; j < 4; j++) acc[i][j] = 0.f;

    for (int k0 = 0; k0 < 384; k0 += 32) {
        __syncthreads();
#pragma unroll
        for (int l = 0; l < 2; l++) {
            int idx = t * 2 + l;
            int r = idx >> 3, c4 = (idx & 7) * 4;
            float4 a = *(const float4*)(x + (size_t)(m0 + r) * 384 + k0 + c4);
            As[c4 + 0][r] = a.x;
            As[c4 + 1][r] = a.y;
            As[c4 + 2][r] = a.z;
            As[c4 + 3][r] = a.w;
        }
#pragma unroll
        for (int l = 0; l < 2; l++) {
            int idx = t * 2 + l;
            int kr = idx >> 4, cc = (idx & 15) * 4;
            *(float4*)&Bs[kr][cc] = *(const float4*)(w + (size_t)(k0 + kr) * 1152 + c0 + cc);
        }
        __syncthreads();
#pragma unroll
        for (int kk = 0; kk < 32; kk++) {
            float4 a = *(float4*)&As[kk][ty * 4];
            float4 bb = *(float4*)&Bs[kk][tx * 4];
            float av[4] = {a.x, a.y, a.z, a.w};
            float bv[4] = {bb.x, bb.y, bb.z, bb.w};
#pragma unroll
            for (int i = 0; i < 4; i++)
#pragma unroll
                for (int j = 0; j < 4; j++) acc[i][j] += av[i] * bv[j];
        }
    }
    const int sec = (c0 + tx * 4) / 384;           // 0=q, 1=k, 2=v (uniform per block)
    float* dst = (sec == 0) ? qw : (sec == 1) ? kw : vw;
    const int cc0 = c0 + tx * 4 - sec * 384;
    const int h = cc0 >> 5, dd = cc0 & 31;
#pragma unroll
    for (int i = 0; i < 4; i++) {
        int row = m0 + ty * 4 + i;
        int b = row >> 10, n = row & 1023;
        float4 o;
        if (sec < 2) {
            o.x = fmaxf(acc[i][0], 0.f) + EPS;
            o.y = fmaxf(acc[i][1], 0.f) + EPS;
            o.z = fmaxf(acc[i][2], 0.f) + EPS;
            o.w = fmaxf(acc[i][3], 0.f) + EPS;
        } else {
            o = make_float4(acc[i][0], acc[i][1], acc[i][2], acc[i][3]);
        }
        *(float4*)(dst + (size_t)((b * 12 + h) * 1024 + n) * 32 + dd) = o;
    }
}

// ---------------- Kernel 2: Toeplitz-masked linear attention ----------------
// q,k,v: [48][1024][32]; tw: [2047]; op: [4096][384]
// R3-identical arithmetic (f32 S, f64 num/den accumulation, m-order 0..1023).
// n-tile 32 rows (grid 32x48=1536 blocks); LDS 31.0 KB -> 5 blocks/CU, 20 waves/CU
// (R6 was 52.7KB -> 3 blocks, occupancy 18.5%, latency-bound at no-pipe-saturated).
// V stays f32 in LDS: R3->R6 showed cvts are free (VALUBusy 68->43 at same time).
// PV: thread owns 1 row x 4 cols: per m = 1 ds_read_b32 + 1 ds_read_b128 + 5 f64 ops.
__global__ __launch_bounds__(256) void toep_attn(const float* __restrict__ q,
                                                 const float* __restrict__ k,
                                                 const float* __restrict__ v,
                                                 const float* __restrict__ tw,
                                                 float* __restrict__ op) {
    const int t = threadIdx.x;
    const int n0 = blockIdx.x * 32;
    const int bh = blockIdx.y;
    const int b = bh / 12, h = bh % 12;
    __shared__ float Qt[32][36];    // transposed Q: Qt[d][r], r in [0,32)
    __shared__ float Kt[32][68];    // transposed K: Kt[d][m], m in [0,64)
    __shared__ float Vs[64][36];    // natural V (PV reads are broadcasts)
    __shared__ float Ss[32][68];    // masked scores
    __shared__ float Ts[128];       // Toeplitz window (96 used)

    const float* qb = q + (size_t)bh * 32768;
    const float* kb = k + (size_t)bh * 32768;
    const float* vb = v + (size_t)bh * 32768;

    // stage Q transposed (once): 32 rows x 32 d = 256 float4
    {
        int r = t >> 3, c4 = (t & 7) * 4;
        float4 a = *(const float4*)(qb + (size_t)(n0 + r) * 32 + c4);
        Qt[c4 + 0][r] = a.x;
        Qt[c4 + 1][r] = a.y;
        Qt[c4 + 2][r] = a.z;
        Qt[c4 + 3][r] = a.w;
    }

    float4 kreg[2], vreg[2];
    // prologue: load + stage m-tile 0
#pragma unroll
    for (int l = 0; l < 2; l++) {
        int idx = t * 2 + l;
        int r = idx >> 3, c4 = (idx & 7) * 4;
        kreg[l] = *(const float4*)(kb + (size_t)r * 32 + c4);
        vreg[l] = *(const float4*)(vb + idx * 4);
    }
#pragma unroll
    for (int l = 0; l < 2; l++) {
        int idx = t * 2 + l;
        int r = idx >> 3, c4 = (idx & 7) * 4;
        Kt[c4 + 0][r] = kreg[l].x;
        Kt[c4 + 1][r] = kreg[l].y;
        Kt[c4 + 2][r] = kreg[l].z;
        Kt[c4 + 3][r] = kreg[l].w;
        *(float4*)&Vs[r][c4] = vreg[l];
    }
    // T window: index (n0+r)-(m0+m)+1023 = (n0-m0+960) + (r-m+63); r<32, m<64 -> j in [0,95)
    if (t < 95) Ts[t] = tw[n0 + 960 + t];
    __syncthreads();

    const int sy = t >> 4, sx = t & 15;   // S-phase: rows {2sy,2sy+1}, cols {4sx..+3}
    const int pr = t >> 3;                // PV: row pr, cols pc..pc+3
    const int pc = (t & 7) * 4;
    double num[4] = {0, 0, 0, 0};
    double den = 0.0;

    for (int tt = 0; tt < 16; tt++) {
        const int m0 = tt * 64;
        // issue next tile's K/V loads (latency hides under S + PV)
        if (tt < 15) {
#pragma unroll
            for (int l = 0; l < 2; l++) {
                int idx = t * 2 + l;
                int r = idx >> 3, c4 = (idx & 7) * 4;
                kreg[l] = *(const float4*)(kb + (size_t)(m0 + 64 + r) * 32 + c4);
                vreg[l] = *(const float4*)(vb + (size_t)(m0 + 64) * 32 + idx * 4);
            }
        }

        // S = (Q K^T) * T   (32 rows x 64 cols, f32 - same arithmetic as R3)
        float acc[2][4];
#pragma unroll
        for (int i = 0; i < 2; i++)
#pragma unroll
            for (int j = 0; j < 4; j++) acc[i][j] = 0.f;
#pragma unroll
        for (int kk = 0; kk < 32; kk++) {
            float2 qa = *(float2*)&Qt[kk][sy * 2];
            float4 kb4 = *(float4*)&Kt[kk][sx * 4];
            float av[2] = {qa.x, qa.y};
            float bv[4] = {kb4.x, kb4.y, kb4.z, kb4.w};
#pragma unroll
            for (int i = 0; i < 2; i++)
#pragma unroll
                for (int j = 0; j < 4; j++) acc[i][j] += av[i] * bv[j];
        }
#pragma unroll
        for (int i = 0; i < 2; i++) {
            int r = sy * 2 + i;
            float4 srow;
            srow.x = acc[i][0] * Ts[r - sx * 4 + 63];
            srow.y = acc[i][1] * Ts[r - sx * 4 + 62];
            srow.z = acc[i][2] * Ts[r - sx * 4 + 61];
            srow.w = acc[i][3] * Ts[r - sx * 4 + 60];
            *(float4*)&Ss[r][sx * 4] = srow;
        }
        __syncthreads();   // b1: Ss ready; Kt/Ts dead -> restage for next tile

        if (tt < 15) {
#pragma unroll
            for (int l = 0; l < 2; l++) {
                int idx = t * 2 + l;
                int r = idx >> 3, c4 = (idx & 7) * 4;
                Kt[c4 + 0][r] = kreg[l].x;
                Kt[c4 + 1][r] = kreg[l].y;
                Kt[c4 + 2][r] = kreg[l].z;
                Kt[c4 + 3][r] = kreg[l].w;
            }
            if (t < 95) Ts[t] = tw[n0 - (m0 + 64) + 960 + t];
        }

        // PV: num += S.V ; den += S.1  (f64 accumulation - same ops/order as R3)
#pragma unroll 4
        for (int m = 0; m < 64; m++) {
            double s = (double)Ss[pr][m];
            float4 vv = *(float4*)&Vs[m][pc];
            den += s;
            num[0] += s * (double)vv.x;
            num[1] += s * (double)vv.y;
            num[2] += s * (double)vv.z;
            num[3] += s * (double)vv.w;
        }
        __syncthreads();   // b2: PV done -> Vs free; Kt/Ts visible for next S
        if (tt < 15) {
#pragma unroll
            for (int l = 0; l < 2; l++) {
                int idx = t * 2 + l;
                int r = idx >> 3, c4 = (idx & 7) * 4;
                *(float4*)&Vs[r][c4] = vreg[l];
            }
        }
    }
    double inv = 1.0 / (den + (double)EPS);
    float* o = op + (size_t)((b * 1024) + n0 + pr) * 384 + h * 32 + pc;
    float4 o0 = {(float)(num[0] * inv), (float)(num[1] * inv),
                 (float)(num[2] * inv), (float)(num[3] * inv)};
    *(float4*)o = o0;
}

// ---------------- Kernel 3: out = op @ w_out^T + b_out ----------------
__global__ __launch_bounds__(256) void out_gemm(const float* __restrict__ a,
                                                const float* __restrict__ w,
                                                const float* __restrict__ bias,
                                                float* __restrict__ out) {
    __shared__ float As[32][68];   // As[k][row]
    __shared__ float Bs[32][68];   // Bs[k][cout] = w[cout][k] transposed
    const int t = threadIdx.x;
    const int m0 = blockIdx.y * 64;
    const int c0 = blockIdx.x * 64;
    const int tx = t & 15, ty = t >> 4;

    float acc[4][4];
#pragma unroll
    for (int i = 0; i < 4; i++)
#pragma unroll
        for (int j = 0; j < 4; j++) acc[i][j] = 0.f;

    for (int k0 = 0; k0 < 384; k0 += 32) {
        __syncthreads();
#pragma unroll
        for (int l = 0; l < 2; l++) {
            int idx = t * 2 + l;
            int r = idx >> 3, c4 = (idx & 7) * 4;
            float4 av = *(const float4*)(a + (size_t)(m0 + r) * 384 + k0 + c4);
            As[c4 + 0][r] = av.x;
            As[c4 + 1][r] = av.y;
            As[c4 + 2][r] = av.z;
            As[c4 + 3][r] = av.w;
        }
#pragma unroll
        for (int l = 0; l < 2; l++) {
            int idx = t * 2 + l;
            int r = idx >> 3, c4 = (idx & 7) * 4;
            float4 wv = *(const float4*)(w + (size_t)(c0 + r) * 384 + k0 + c4);
            Bs[c4 + 0][r] = wv.x;
            Bs[c4 + 1][r] = wv.y;
            Bs[c4 + 2][r] = wv.z;
            Bs[c4 + 3][r] = wv.w;
        }
        __syncthreads();
#pragma unroll
        for (int kk = 0; kk < 32; kk++) {
            float4 a4 = *(float4*)&As[kk][ty * 4];
            float4 b4 = *(float4*)&Bs[kk][tx * 4];
            float av[4] = {a4.x, a4.y, a4.z, a4.w};
            float bv[4] = {b4.x, b4.y, b4.z, b4.w};
#pragma unroll
            for (int i = 0; i < 4; i++)
#pragma unroll
                for (int j = 0; j < 4; j++) acc[i][j] += av[i] * bv[j];
        }
    }
    const int col = c0 + tx * 4;
    float4 bb = *(const float4*)(bias + col);
#pragma unroll
    for (int i = 0; i < 4; i++) {
        int row = m0 + ty * 4 + i;
        float4 o = {acc[i][0] + bb.x, acc[i][1] + bb.y,
                    acc[i][2] + bb.z, acc[i][3] + bb.w};
        *(float4*)(out + (size_t)row * 384 + col) = o;
    }
}

extern "C" void kernel_launch(void* const* d_in, const int* in_sizes, int n_in,
                              void* d_out, int out_size, void* d_ws, size_t ws_size,
                              hipStream_t stream) {
    const float* x     = (const float*)d_in[0];
    const float* w_qkv = (const float*)d_in[1];
    const float* w_out = (const float*)d_in[2];
    const float* b_out = (const float*)d_in[3];
    const float* tw    = (const float*)d_in[4];
    float* out = (float*)d_out;

    float* qw = (float*)d_ws;            // 48*1024*32 = 1572864 floats
    float* kw = qw + 1572864;
    float* vw = kw + 1572864;
    float* op = vw + 1572864;            // 4096*384  = 1572864 floats

    qkv_gemm<<<dim3(18, 64), 256, 0, stream>>>(x, w_qkv, qw, kw, vw);
    toep_attn<<<dim3(32, 48), 256, 0, stream>>>(qw, kw, vw, tw, op);
    out_gemm<<<dim3(6, 64), 256, 0, stream>>>(op, w_out, b_out, out);
}

// Round 8
// 324.415 us; speedup vs baseline: 1.0283x; 1.0283x over previous
//
#include <hip/hip_runtime.h>

#define EPS 1e-6f

// Sizes (fixed): B=4, N=1024, DIM=384, H=12, d=32, BH=48
// ws layout (floats): q[48*1024*32] | k[...] | v[...] | out_pre[4096*384]

// ---------------- Kernel 1: qkv = x @ w_qkv, relu+eps on q,k, scatter to [BH][N][32] ----------------
__global__ __launch_bounds__(256) void qkv_gemm(const float* __restrict__ x,
                                                const float* __restrict__ w,
                                                float* __restrict__ qw,
                                                float* __restrict__ kw,
                                                float* __restrict__ vw) {
    __shared__ float As[32][68];   // transposed A tile: As[k][row]
    __shared__ float Bs[32][68];   // natural B tile:    Bs[k][col]
    const int t = threadIdx.x;
    const int m0 = blockIdx.y * 64;
    const int c0 = blockIdx.x * 64;
    const int tx = t & 15, ty = t >> 4;

    float acc[4][4];
#pragma unroll
    for (int i = 0; i < 4; i++)
#pragma unroll
        for (int j = 0; j < 4; j++) acc[i][j] = 0.f;

    for (int k0 = 0; k0 < 384; k0 += 32) {
        __syncthreads();
#pragma unroll
        for (int l = 0; l < 2; l++) {
            int idx = t * 2 + l;
            int r = idx >> 3, c4 = (idx & 7) * 4;
            float4 a = *(const float4*)(x + (size_t)(m0 + r) * 384 + k0 + c4);
            As[c4 + 0][r] = a.x;
            As[c4 + 1][r] = a.y;
            As[c4 + 2][r] = a.z;
            As[c4 + 3][r] = a.w;
        }
#pragma unroll
        for (int l = 0; l < 2; l++) {
            int idx = t * 2 + l;
            int kr = idx >> 4, cc = (idx & 15) * 4;
            *(float4*)&Bs[kr][cc] = *(const float4*)(w + (size_t)(k0 + kr) * 1152 + c0 + cc);
        }
        __syncthreads();
#pragma unroll
        for (int kk = 0; kk < 32; kk++) {
            float4 a = *(float4*)&As[kk][ty * 4];
            float4 bb = *(float4*)&Bs[kk][tx * 4];
            float av[4] = {a.x, a.y, a.z, a.w};
            float bv[4] = {bb.x, bb.y, bb.z, bb.w};
#pragma unroll
            for (int i = 0; i < 4; i++)
#pragma unroll
                for (int j = 0; j < 4; j++) acc[i][j] += av[i] * bv[j];
        }
    }
    const int sec = (c0 + tx * 4) / 384;           // 0=q, 1=k, 2=v (uniform per block)
    float* dst = (sec == 0) ? qw : (sec == 1) ? kw : vw;
    const int cc0 = c0 + tx * 4 - sec * 384;
    const int h = cc0 >> 5, dd = cc0 & 31;
#pragma unroll
    for (int i = 0; i < 4; i++) {
        int row = m0 + ty * 4 + i;
        int b = row >> 10, n = row & 1023;
        float4 o;
        if (sec < 2) {
            o.x = fmaxf(acc[i][0], 0.f) + EPS;
            o.y = fmaxf(acc[i][1], 0.f) + EPS;
            o.z = fmaxf(acc[i][2], 0.f) + EPS;
            o.w = fmaxf(acc[i][3], 0.f) + EPS;
        } else {
            o = make_float4(acc[i][0], acc[i][1], acc[i][2], acc[i][3]);
        }
        *(float4*)(dst + (size_t)((b * 12 + h) * 1024 + n) * 32 + dd) = o;
    }
}

// ---------------- Kernel 2: Toeplitz-masked linear attention ----------------
// q,k,v: [48][1024][32]; tw: [2047]; op: [4096][384]
// LDS-instruction diet vs R6/R7 (which were LDS-pipe-bound at ~195 us):
//  * S stored TRANSPOSED St[m][r] -> PV reads 4 rows of S per ds_read_b128.
//  * Each PV thread owns 4 rows x 4 cols; tile's m-axis split by thread parity
//    (t&1): 32 m-steps/thread, partner does the other 32; one f64 shfl_xor
//    reduction at the end (f64 add commutative -> partners bitwise agree).
//  * Per m-step: 2 ds_read_b128 -> 16 f64 FMA (R6: 5 LDS per 8 FMA).
// S arithmetic bit-identical to R3/R6 (f32 fma chain, kk ascending); num/den
// f64 with only order changed (f64-eps-level difference).
__global__ __launch_bounds__(256) void toep_attn(const float* __restrict__ q,
                                                 const float* __restrict__ k,
                                                 const float* __restrict__ v,
                                                 const float* __restrict__ tw,
                                                 float* __restrict__ op) {
    const int t = threadIdx.x;
    const int n0 = blockIdx.x * 64;
    const int bh = blockIdx.y;
    const int b = bh / 12, h = bh % 12;
    __shared__ float Qt[32][68];    // transposed Q: Qt[d][r]
    __shared__ float Kt[32][68];    // transposed K: Kt[d][m]
    __shared__ float Vs[64][36];    // natural V
    __shared__ float St[64][68];    // TRANSPOSED masked scores: St[m][r]
    __shared__ float Ts[128];       // Toeplitz window

    const float* qb = q + (size_t)bh * 32768;
    const float* kb = k + (size_t)bh * 32768;
    const float* vb = v + (size_t)bh * 32768;

    // stage Q transposed (once): 64 rows x 32 d
#pragma unroll
    for (int l = 0; l < 2; l++) {
        int idx = t * 2 + l;
        int r = idx >> 3, c4 = (idx & 7) * 4;
        float4 a = *(const float4*)(qb + (size_t)(n0 + r) * 32 + c4);
        Qt[c4 + 0][r] = a.x;
        Qt[c4 + 1][r] = a.y;
        Qt[c4 + 2][r] = a.z;
        Qt[c4 + 3][r] = a.w;
    }

    float4 kreg[2], vreg[2];
    // prologue: load + stage m-tile 0
#pragma unroll
    for (int l = 0; l < 2; l++) {
        int idx = t * 2 + l;
        int r = idx >> 3, c4 = (idx & 7) * 4;
        kreg[l] = *(const float4*)(kb + (size_t)r * 32 + c4);
        vreg[l] = *(const float4*)(vb + (size_t)r * 32 + c4);
    }
#pragma unroll
    for (int l = 0; l < 2; l++) {
        int idx = t * 2 + l;
        int r = idx >> 3, c4 = (idx & 7) * 4;
        Kt[c4 + 0][r] = kreg[l].x;
        Kt[c4 + 1][r] = kreg[l].y;
        Kt[c4 + 2][r] = kreg[l].z;
        Kt[c4 + 3][r] = kreg[l].w;
        *(float4*)&Vs[r][c4] = vreg[l];
    }
    if (t < 127) Ts[t] = tw[n0 + 960 + t];
    __syncthreads();

    // S-phase mapping: 4 rows x 4 m micro-tile
    const int rgrp = t & 15;        // rows 4*rgrp..+3
    const int mgrp = t >> 4;        // m    4*mgrp..+3
    // PV mapping: 4 rows x 4 cols, m split by parity
    const int mhalf = t & 1;
    const int rgrp2 = (t >> 1) & 15;  // rows 4*rgrp2..+3
    const int cgrp = t >> 5;          // cols 4*cgrp..+3

    double num[4][4];
#pragma unroll
    for (int i = 0; i < 4; i++)
#pragma unroll
        for (int j = 0; j < 4; j++) num[i][j] = 0.0;
    double den[4] = {0.0, 0.0, 0.0, 0.0};

    for (int tt = 0; tt < 16; tt++) {
        const int m0 = tt * 64;
        // issue next tile's K/V loads (latency hides under S + PV)
        if (tt < 15) {
#pragma unroll
            for (int l = 0; l < 2; l++) {
                int idx = t * 2 + l;
                int r = idx >> 3, c4 = (idx & 7) * 4;
                kreg[l] = *(const float4*)(kb + (size_t)(m0 + 64 + r) * 32 + c4);
                vreg[l] = *(const float4*)(vb + (size_t)(m0 + 64 + r) * 32 + c4);
            }
        }

        // S = (Q K^T): acc[i=row][j=m], bit-identical fma chain to R3/R6
        float acc[4][4];
#pragma unroll
        for (int i = 0; i < 4; i++)
#pragma unroll
            for (int j = 0; j < 4; j++) acc[i][j] = 0.f;
#pragma unroll
        for (int kk = 0; kk < 32; kk++) {
            float4 qv = *(float4*)&Qt[kk][rgrp * 4];
            float4 kv = *(float4*)&Kt[kk][mgrp * 4];
            float av[4] = {qv.x, qv.y, qv.z, qv.w};
            float bv[4] = {kv.x, kv.y, kv.z, kv.w};
#pragma unroll
            for (int i = 0; i < 4; i++)
#pragma unroll
                for (int j = 0; j < 4; j++) acc[i][j] += av[i] * bv[j];
        }
        // mask + write transposed: St[m][4*rgrp..+3] per j (b128 stores)
#pragma unroll
        for (int j = 0; j < 4; j++) {
            int m = mgrp * 4 + j;
            int tb = rgrp * 4 - m + 63;
            float4 srow;
            srow.x = acc[0][j] * Ts[tb + 0];
            srow.y = acc[1][j] * Ts[tb + 1];
            srow.z = acc[2][j] * Ts[tb + 2];
            srow.w = acc[3][j] * Ts[tb + 3];
            *(float4*)&St[m][rgrp * 4] = srow;
        }
        __syncthreads();   // b1: St ready; Kt/Ts dead -> restage

        if (tt < 15) {
#pragma unroll
            for (int l = 0; l < 2; l++) {
                int idx = t * 2 + l;
                int r = idx >> 3, c4 = (idx & 7) * 4;
                Kt[c4 + 0][r] = kreg[l].x;
                Kt[c4 + 1][r] = kreg[l].y;
                Kt[c4 + 2][r] = kreg[l].z;
                Kt[c4 + 3][r] = kreg[l].w;
            }
            if (t < 127) Ts[t] = tw[n0 - (m0 + 64) + 960 + t];
        }

        // PV: 32 m-steps (parity mhalf); per step 2 b128 reads -> 16 f64 FMA + 4 f64 add
#pragma unroll 4
        for (int m2 = 0; m2 < 32; m2++) {
            int m = 2 * m2 + mhalf;
            float4 s4 = *(float4*)&St[m][rgrp2 * 4];
            float4 v4 = *(float4*)&Vs[m][cgrp * 4];
            double sd[4] = {(double)s4.x, (double)s4.y, (double)s4.z, (double)s4.w};
            double vd[4] = {(double)v4.x, (double)v4.y, (double)v4.z, (double)v4.w};
#pragma unroll
            for (int i = 0; i < 4; i++) {
                den[i] += sd[i];
#pragma unroll
                for (int j = 0; j < 4; j++) num[i][j] += sd[i] * vd[j];
            }
        }
        __syncthreads();   // b2: PV done -> St/Vs free; Kt/Ts visible for next S
        if (tt < 15) {
#pragma unroll
            for (int l = 0; l < 2; l++) {
                int idx = t * 2 + l;
                int r = idx >> 3, c4 = (idx & 7) * 4;
                *(float4*)&Vs[r][c4] = vreg[l];
            }
        }
    }

    // combine m-parity halves with partner thread (t^1); f64 add is commutative
#pragma unroll
    for (int i = 0; i < 4; i++) {
        den[i] += __shfl_xor(den[i], 1);
#pragma unroll
        for (int j = 0; j < 4; j++) num[i][j] += __shfl_xor(num[i][j], 1);
    }
    // each thread writes 2 of its 4 rows (split by mhalf)
#pragma unroll
    for (int rr = 0; rr < 2; rr++) {
        int i = 2 * mhalf + rr;
        double inv = 1.0 / (den[i] + (double)EPS);
        int row = n0 + rgrp2 * 4 + i;
        float4 o = {(float)(num[i][0] * inv), (float)(num[i][1] * inv),
                    (float)(num[i][2] * inv), (float)(num[i][3] * inv)};
        *(float4*)(op + (size_t)(b * 1024 + row) * 384 + h * 32 + cgrp * 4) = o;
    }
}

// ---------------- Kernel 3: out = op @ w_out^T + b_out ----------------
__global__ __launch_bounds__(256) void out_gemm(const float* __restrict__ a,
                                                const float* __restrict__ w,
                                                const float* __restrict__ bias,
                                                float* __restrict__ out) {
    __shared__ float As[32][68];   // As[k][row]
    __shared__ float Bs[32][68];   // Bs[k][cout] = w[cout][k] transposed
    const int t = threadIdx.x;
    const int m0 = blockIdx.y * 64;
    const int c0 = blockIdx.x * 64;
    const int tx = t & 15, ty = t >> 4;

    float acc[4][4];
#pragma unroll
    for (int i = 0; i < 4; i++)
#pragma unroll
        for (int j = 0; j < 4; j++) acc[i][j] = 0.f;

    for (int k0 = 0; k0 < 384; k0 += 32) {
        __syncthreads();
#pragma unroll
        for (int l = 0; l < 2; l++) {
            int idx = t * 2 + l;
            int r = idx >> 3, c4 = (idx & 7) * 4;
            float4 av = *(const float4*)(a + (size_t)(m0 + r) * 384 + k0 + c4);
            As[c4 + 0][r] = av.x;
            As[c4 + 1][r] = av.y;
            As[c4 + 2][r] = av.z;
            As[c4 + 3][r] = av.w;
        }
#pragma unroll
        for (int l = 0; l < 2; l++) {
            int idx = t * 2 + l;
            int r = idx >> 3, c4 = (idx & 7) * 4;
            float4 wv = *(const float4*)(w + (size_t)(c0 + r) * 384 + k0 + c4);
            Bs[c4 + 0][r] = wv.x;
            Bs[c4 + 1][r] = wv.y;
            Bs[c4 + 2][r] = wv.z;
            Bs[c4 + 3][r] = wv.w;
        }
        __syncthreads();
#pragma unroll
        for (int kk = 0; kk < 32; kk++) {
            float4 a4 = *(float4*)&As[kk][ty * 4];
            float4 b4 = *(float4*)&Bs[kk][tx * 4];
            float av[4] = {a4.x, a4.y, a4.z, a4.w};
            float bv[4] = {b4.x, b4.y, b4.z, b4.w};
#pragma unroll
            for (int i = 0; i < 4; i++)
#pragma unroll
                for (int j = 0; j < 4; j++) acc[i][j] += av[i] * bv[j];
        }
    }
    const int col = c0 + tx * 4;
    float4 bb = *(const float4*)(bias + col);
#pragma unroll
    for (int i = 0; i < 4; i++) {
        int row = m0 + ty * 4 + i;
        float4 o = {acc[i][0] + bb.x, acc[i][1] + bb.y,
                    acc[i][2] + bb.z, acc[i][3] + bb.w};
        *(float4*)(out + (size_t)row * 384 + col) = o;
    }
}

extern "C" void kernel_launch(void* const* d_in, const int* in_sizes, int n_in,
                              void* d_out, int out_size, void* d_ws, size_t ws_size,
                              hipStream_t stream) {
    const float* x     = (const float*)d_in[0];
    const float* w_qkv = (const float*)d_in[1];
    const float* w_out = (const float*)d_in[2];
    const float* b_out = (const float*)d_in[3];
    const float* tw    = (const float*)d_in[4];
    float* out = (float*)d_out;

    float* qw = (float*)d_ws;            // 48*1024*32 = 1572864 floats
    float* kw = qw + 1572864;
    float* vw = kw + 1572864;
    float* op = vw + 1572864;            // 4096*384  = 1572864 floats

    qkv_gemm<<<dim3(18, 64), 256, 0, stream>>>(x, w_qkv, qw, kw, vw);
    toep_attn<<<dim3(16, 48), 256, 0, stream>>>(qw, kw, vw, tw, op);
    out_gemm<<<dim3(6, 64), 256, 0, stream>>>(op, w_out, b_out, out);
}